// Round 11
// baseline (140.414 us; speedup 1.0000x reference)
//
#include <hip/hip_runtime.h>
#include <math.h>

// EdgeConditionedConv on MI355X — round 10: slim-wave nt-split edge_msg.
// r5/r7 both pinned at ~20% occupancy: hf[4][4]=64 regs -> ~176 unified
// regs/wave -> 2 waves/SIMD regardless of wave count. Now wave=(mt,nh):
// 16 i-rows x 32 edges, hf[2][4]=32 regs, live set ~100 -> 4-5 waves/SIMD.
// Same MFMA count, same math order as r9 (proven numerics).
// prep/gru identical to r9.

constexpr int N_NODES  = 25000;
constexpr int N_EDGES  = 50000;
constexpr int NODE_DIM = 64;
constexpr int EDGE_DIM = 16;
constexpr int HID      = 128;

typedef __attribute__((ext_vector_type(8))) _Float16 half8;
typedef __attribute__((ext_vector_type(4))) float    f32x4;

constexpr int G_MS  = 128;             // agg-zero blocks
constexpr int G_PK  = 355;             // prepack blocks
constexpr int G_MLP = N_EDGES / 8;     // mlp1 blocks (8 edges each)

// ---------------------------------------------------------------- prep
__global__ __launch_bounds__(256) void prep_kernel(
    const float* __restrict__ W2, const float* __restrict__ b2,
    const float* __restrict__ w_ih, const float* __restrict__ w_hh,
    const float* __restrict__ edge_attr, const float* __restrict__ W1,
    const float* __restrict__ b1,
    _Float16* __restrict__ Wpk, _Float16* __restrict__ b2pk,
    float* __restrict__ wTih, float* __restrict__ wThh,
    _Float16* __restrict__ h, float* __restrict__ agg)
{
    int b = blockIdx.x;
    if (b < G_MS) {
        float4* a4 = (float4*)agg;
        const float4 z = make_float4(0.f, 0.f, 0.f, 0.f);
        for (int i = b * 256 + threadIdx.x; i < N_NODES * NODE_DIM / 4; i += G_MS * 256)
            a4[i] = z;
        return;
    }
    if (b < G_MS + G_PK) {
        int c = (b - G_MS) * 256 + threadIdx.x;
        if (c < 65536) {
            int lane = c & 63, mt = (c >> 6) & 3, ks = (c >> 8) & 3, j = c >> 10;
            int i   = mt * 16 + (lane & 15);
            int col = ks * 32 + ((lane >> 4) & 3) * 8;
            const float* src = W2 + (size_t)(i * 64 + j) * HID + col;
            half8 o;
#pragma unroll
            for (int q = 0; q < 8; ++q) o[q] = (_Float16)src[q];
            ((half8*)Wpk)[c] = o;
        } else if (c < 65536 + 512) {
            int c2 = c - 65536;
            int lane = c2 & 63, mt = (c2 >> 6) & 3, ks2 = (c2 >> 8) & 1;
            int i = mt * 16 + (lane & 15);
            int j = ks2 * 32 + ((lane >> 4) & 3) * 8;
            const float* src = b2 + i * 64 + j;
            half8 o;
#pragma unroll
            for (int q = 0; q < 8; ++q) o[q] = (_Float16)src[q];
            ((half8*)b2pk)[c2] = o;
        } else if (c < 65536 + 512 + 2 * 12288) {
            int idx = c - (65536 + 512);
            const float* src = (idx < 12288) ? w_ih : w_hh;
            float*       dst = (idx < 12288) ? wTih : wThh;
            int e2 = (idx < 12288) ? idx : idx - 12288;
            int k = e2 / 192, g = e2 - k * 192;
            dst[k * 192 + g] = src[(size_t)g * 64 + k];
        }
        return;
    }
    // mlp1: 8 edges per block
    int ebase = (b - G_MS - G_PK) * 8;
    int k = threadIdx.x & 127;
    const float* w = W1 + (size_t)k * EDGE_DIM;
#pragma unroll
    for (int p = 0; p < 4; ++p) {
        int e = ebase + p * 2 + (threadIdx.x >> 7);
        if (e >= N_EDGES) break;
        const float* ea = edge_attr + (size_t)e * EDGE_DIM;
        float acc = b1[k];
#pragma unroll
        for (int d = 0; d < EDGE_DIM; ++d) acc += ea[d] * w[d];
        float g = 0.5f * acc * (1.0f + erff(acc * 0.70710678118654752f));
        h[(size_t)e * HID + k] = (_Float16)g;
    }
}

// ---------------------------------------------------------------- phase 2
// 8 waves: wave = (nh, mt). Wave owns i-rows [mt*16, mt*16+16) x edges
// [nh*32, nh*32+32) over ALL j. hf[2][4] = 32 regs (the occupancy lever).
__global__ __launch_bounds__(512, 2) void edge_msg_mfma_kernel(
    const _Float16* __restrict__ hbuf,
    const float*    __restrict__ x,
    const int*      __restrict__ edge_index,   // [2][E] int32
    const _Float16* __restrict__ Wpk,
    const _Float16* __restrict__ b2pk,
    float* __restrict__ agg)                   // [N][64], pre-zeroed
{
    __shared__ float xsh[64 * 68];      // gathered x[src], pitch 68
    __shared__ float msgred[64 * 67];   // [i][e], pitch 67
    __shared__ int   dsts[64];

    const int e0   = blockIdx.x * 64;
    const int t    = threadIdx.x;
    const int wave = t >> 6;
    const int lane = t & 63;
    const int mt   = wave & 3;          // i-row block
    const int nh   = wave >> 2;         // edge half

    // ---- gather x[src[e]] rows into xsh (zero-fill invalid) + dsts
    if (t < 64) dsts[t] = (e0 + t < N_EDGES) ? edge_index[N_EDGES + e0 + t] : -1;
#pragma unroll
    for (int r = 0; r < 2; ++r) {
        int idx = t + r * 512;            // 0..1023 float4 slots
        int le = idx >> 4, q = idx & 15;
        int e = e0 + le;
        float4 v = make_float4(0.f, 0.f, 0.f, 0.f);
        if (e < N_EDGES) {
            int s = edge_index[e];
            if ((unsigned)s < (unsigned)N_NODES)
                v = ((const float4*)x)[(size_t)s * 16 + q];
        }
        *(float4*)&xsh[le * 68 + q * 4] = v;
    }

    // ---- per-wave resident h fragments: 2 edge tiles (nh half)
    half8 hf[2][4];   // [nt][ks]
#pragma unroll
    for (int nt = 0; nt < 2; ++nt) {
#pragma unroll
        for (int ks = 0; ks < 4; ++ks) {
            int el = (nh * 2 + nt) * 16 + (lane & 15);
            int ee = e0 + el; if (ee >= N_EDGES) ee = N_EDGES - 1;
            int gk = ks * 32 + ((lane >> 4) & 3) * 8;
            hf[nt][ks] = *(const half8*)(hbuf + (size_t)ee * HID + gk);
        }
    }
    __syncthreads();

    const f32x4 zero4 = {0.f, 0.f, 0.f, 0.f};
    f32x4 msg[2];
#pragma unroll
    for (int nt = 0; nt < 2; ++nt) msg[nt] = zero4;

    const half8* wpk8 = (const half8*)Wpk;
    const int mbase = mt * 64 + lane;

    half8 aA[4], aB[4];
#pragma unroll
    for (int ks = 0; ks < 4; ++ks) aA[ks] = wpk8[(size_t)mbase + ks * 256];  // j=0

#pragma unroll 1
    for (int j = 0; j < 64; j += 2) {
        {   // prefetch j+1
            size_t nb = (size_t)(j + 1) * 1024 + mbase;
#pragma unroll
            for (int ks = 0; ks < 4; ++ks) aB[ks] = wpk8[nb + ks * 256];
        }
        {   // compute j
            float gv[2];
#pragma unroll
            for (int nt = 0; nt < 2; ++nt)
                gv[nt] = xsh[((nh * 2 + nt) * 16 + (lane & 15)) * 68 + j];
            f32x4 P[2];
#pragma unroll
            for (int ks = 0; ks < 4; ++ks)
#pragma unroll
                for (int nt = 0; nt < 2; ++nt)
                    P[nt] = __builtin_amdgcn_mfma_f32_16x16x32_f16(
                        aA[ks], hf[nt][ks], ks == 0 ? zero4 : P[nt], 0, 0, 0);
#pragma unroll
            for (int nt = 0; nt < 2; ++nt)
#pragma unroll
                for (int r = 0; r < 4; ++r) msg[nt][r] += gv[nt] * P[nt][r];
        }
        if (j + 2 < 64) {   // prefetch j+2
            size_t nb = (size_t)(j + 2) * 1024 + mbase;
#pragma unroll
            for (int ks = 0; ks < 4; ++ks) aA[ks] = wpk8[nb + ks * 256];
        }
        {   // compute j+1
            float gv[2];
#pragma unroll
            for (int nt = 0; nt < 2; ++nt)
                gv[nt] = xsh[((nh * 2 + nt) * 16 + (lane & 15)) * 68 + j + 1];
            f32x4 P[2];
#pragma unroll
            for (int ks = 0; ks < 4; ++ks)
#pragma unroll
                for (int nt = 0; nt < 2; ++nt)
                    P[nt] = __builtin_amdgcn_mfma_f32_16x16x32_f16(
                        aB[ks], hf[nt][ks], ks == 0 ? zero4 : P[nt], 0, 0, 0);
#pragma unroll
            for (int nt = 0; nt < 2; ++nt)
#pragma unroll
                for (int r = 0; r < 4; ++r) msg[nt][r] += gv[nt] * P[nt][r];
        }
    }

    // ---- bias: msg[i,e] += sum_j b2[i*64+j]*g[e,j]  (this wave's tile)
#pragma unroll
    for (int ks2 = 0; ks2 < 2; ++ks2) {
        half8 gf[2];
#pragma unroll
        for (int nt = 0; nt < 2; ++nt) {
            const float* gp = &xsh[((nh * 2 + nt) * 16 + (lane & 15)) * 68 + ks2 * 32 + ((lane >> 4) & 3) * 8];
            float4 lo = *(const float4*)gp;
            float4 hi = *(const float4*)(gp + 4);
            half8 g8;
            g8[0] = (_Float16)lo.x; g8[1] = (_Float16)lo.y;
            g8[2] = (_Float16)lo.z; g8[3] = (_Float16)lo.w;
            g8[4] = (_Float16)hi.x; g8[5] = (_Float16)hi.y;
            g8[6] = (_Float16)hi.z; g8[7] = (_Float16)hi.w;
            gf[nt] = g8;
        }
        half8 bf8 = ((const half8*)b2pk)[ks2 * 256 + mt * 64 + lane];
#pragma unroll
        for (int nt = 0; nt < 2; ++nt)
            msg[nt] = __builtin_amdgcn_mfma_f32_16x16x32_f16(bf8, gf[nt], msg[nt], 0, 0, 0);
    }

    // ---- each wave writes its exclusive 16x32 tile of msgred
#pragma unroll
    for (int nt = 0; nt < 2; ++nt)
#pragma unroll
        for (int r = 0; r < 4; ++r) {
            int i = mt * 16 + ((lane >> 4) & 3) * 4 + r;
            int e = (nh * 2 + nt) * 16 + (lane & 15);
            msgred[i * 67 + e] = msg[nt][r];
        }
    __syncthreads();

    // ---- scatter, coalesced: one edge row per atomic instr (lane = dim i)
#pragma unroll 1
    for (int ee = wave; ee < 64; ee += 8) {
        int d = dsts[ee];
        if (e0 + ee < N_EDGES && (unsigned)d < (unsigned)N_NODES)
            atomicAdd(agg + (size_t)d * NODE_DIM + lane, msgred[lane * 67 + ee]);
    }
}

// ---------------------------------------------------------------- phase 3
// GRUCell, transposed-LDS staging (r9, proven).
__global__ __launch_bounds__(256) void gru_kernel(
    const float* __restrict__ agg,
    const float* __restrict__ x,
    const float* __restrict__ wTih,   // [64][192]
    const float* __restrict__ wThh,   // [64][192]
    const float* __restrict__ b_ih,
    const float* __restrict__ b_hh,
    float* __restrict__ out)
{
    __shared__ float asT[4][64][12];  // [wave][k][node]
    __shared__ float xsT[4][64][12];
    const int t    = threadIdx.x;
    const int wave = t >> 6, lane = t & 63;
    const int n0   = blockIdx.x * 32;

    {
        const f32x4* asrc = (const f32x4*)(agg + (size_t)n0 * 64);
        const f32x4* xsrc = (const f32x4*)(x   + (size_t)n0 * 64);
        int nvalid4 = min(N_NODES - n0, 32) * 16;
#pragma unroll
        for (int r = 0; r < 2; ++r) {
            int idx = t + r * 256;
            f32x4 v = {0.f, 0.f, 0.f, 0.f}, u = v;
            if (idx < nvalid4) { v = asrc[idx]; u = xsrc[idx]; }
            int le = idx >> 4, q = idx & 15;
#pragma unroll
            for (int c = 0; c < 4; ++c) {
                asT[le >> 3][q * 4 + c][le & 7] = v[c];
                xsT[le >> 3][q * 4 + c][le & 7] = u[c];
            }
        }
    }
    __syncthreads();

    float accI0[8] = {}, accI1[8] = {}, accI2[8] = {};
    float accH0[8] = {}, accH1[8] = {}, accH2[8] = {};

#pragma unroll 4
    for (int k = 0; k < 64; ++k) {
        f32x4 a03 = *(const f32x4*)&asT[wave][k][0];
        f32x4 a47 = *(const f32x4*)&asT[wave][k][4];
        f32x4 x03 = *(const f32x4*)&xsT[wave][k][0];
        f32x4 x47 = *(const f32x4*)&xsT[wave][k][4];
        float wi0 = wTih[k * 192 + lane];
        float wi1 = wTih[k * 192 + 64 + lane];
        float wi2 = wTih[k * 192 + 128 + lane];
        float wh0 = wThh[k * 192 + lane];
        float wh1 = wThh[k * 192 + 64 + lane];
        float wh2 = wThh[k * 192 + 128 + lane];
#pragma unroll
        for (int n = 0; n < 8; ++n) {
            float a  = (n < 4) ? a03[n] : a47[n - 4];
            float xx = (n < 4) ? x03[n] : x47[n - 4];
            accI0[n] += a * wi0;  accI1[n] += a * wi1;  accI2[n] += a * wi2;
            accH0[n] += xx * wh0; accH1[n] += xx * wh1; accH2[n] += xx * wh2;
        }
    }

    float bi0 = b_ih[lane], bi1 = b_ih[64 + lane], bi2 = b_ih[128 + lane];
    float bh0 = b_hh[lane], bh1 = b_hh[64 + lane], bh2 = b_hh[128 + lane];
#pragma unroll
    for (int n = 0; n < 8; ++n) {
        int node = n0 + wave * 8 + n;
        if (node >= N_NODES) break;
        float r  = 1.f / (1.f + expf(-(accI0[n] + bi0 + accH0[n] + bh0)));
        float z  = 1.f / (1.f + expf(-(accI1[n] + bi1 + accH1[n] + bh1)));
        float nn = tanhf(accI2[n] + bi2 + r * (accH2[n] + bh2));
        float xv = x[(size_t)node * 64 + lane];
        out[(size_t)node * 64 + lane] = (1.f - z) * nn + z * xv;
    }
}

// ---------------------------------------------------------------- launch
extern "C" void kernel_launch(void* const* d_in, const int* in_sizes, int n_in,
                              void* d_out, int out_size, void* d_ws, size_t ws_size,
                              hipStream_t stream)
{
    const float* x          = (const float*)d_in[0];
    const int*   edge_index = (const int*)  d_in[1];
    const float* edge_attr  = (const float*)d_in[2];
    const float* W1         = (const float*)d_in[3];
    const float* b1         = (const float*)d_in[4];
    const float* W2         = (const float*)d_in[5];
    const float* b2         = (const float*)d_in[6];
    const float* w_ih       = (const float*)d_in[7];
    const float* w_hh       = (const float*)d_in[8];
    const float* b_ih       = (const float*)d_in[9];
    const float* b_hh       = (const float*)d_in[10];
    float* out = (float*)d_out;

    // ws layout: byte-identical to round 5/9 (proven; total 20,355,072 B)
    char* ws = (char*)d_ws;
    _Float16* hbuf = (_Float16*)ws;                         // 12.8 MB
    ws += (size_t)N_EDGES * HID * sizeof(_Float16);
    _Float16* Wpk  = (_Float16*)ws;                         // 1 MB
    ws += (size_t)65536 * 8 * sizeof(_Float16);
    _Float16* b2pk = (_Float16*)ws;                         // 8 KB
    ws += (size_t)512 * 8 * sizeof(_Float16);
    float* wTih = (float*)ws;                               // 48 KB
    ws += (size_t)64 * 192 * sizeof(float);
    float* wThh = (float*)ws;                               // 48 KB
    ws += (size_t)64 * 192 * sizeof(float);
    float* agg = (float*)ws;                                // 6.4 MB

    prep_kernel<<<dim3(G_MS + G_PK + G_MLP), dim3(256), 0, stream>>>(
        W2, b2, w_ih, w_hh, edge_attr, W1, b1,
        Wpk, b2pk, wTih, wThh, hbuf, agg);

    edge_msg_mfma_kernel<<<dim3((N_EDGES + 63) / 64), dim3(512), 0, stream>>>(
        hbuf, x, edge_index, Wpk, b2pk, agg);

    gru_kernel<<<dim3((N_NODES + 31) / 32), dim3(256), 0, stream>>>(
        agg, x, wTih, wThh, b_ih, b_hh, out);
}

// Round 12
// 126.908 us; speedup vs baseline: 1.1064x; 1.1064x over previous
//
#include <hip/hip_runtime.h>
#include <math.h>

// EdgeConditionedConv on MI355X — round 11: K-half split edge_msg.
// r10 lesson: occupancy lever must NOT break the per-wave MFMA:A-load ratio
// (4:1). Splitting K (not edges) halves hf (64->32 regs) while keeping 2
// A-loads : 8 MFMA per j. gv epilogue distributes over K-halves; partials
// combine via r7-proven dual-msgred summed scatter. prep/gru = r9.

constexpr int N_NODES  = 25000;
constexpr int N_EDGES  = 50000;
constexpr int NODE_DIM = 64;
constexpr int EDGE_DIM = 16;
constexpr int HID      = 128;

typedef __attribute__((ext_vector_type(8))) _Float16 half8;
typedef __attribute__((ext_vector_type(4))) float    f32x4;

constexpr int G_MS  = 128;             // agg-zero blocks
constexpr int G_PK  = 355;             // prepack blocks
constexpr int G_MLP = N_EDGES / 8;     // mlp1 blocks (8 edges each)

// ---------------------------------------------------------------- prep
__global__ __launch_bounds__(256) void prep_kernel(
    const float* __restrict__ W2, const float* __restrict__ b2,
    const float* __restrict__ w_ih, const float* __restrict__ w_hh,
    const float* __restrict__ edge_attr, const float* __restrict__ W1,
    const float* __restrict__ b1,
    _Float16* __restrict__ Wpk, _Float16* __restrict__ b2pk,
    float* __restrict__ wTih, float* __restrict__ wThh,
    _Float16* __restrict__ h, float* __restrict__ agg)
{
    int b = blockIdx.x;
    if (b < G_MS) {
        float4* a4 = (float4*)agg;
        const float4 z = make_float4(0.f, 0.f, 0.f, 0.f);
        for (int i = b * 256 + threadIdx.x; i < N_NODES * NODE_DIM / 4; i += G_MS * 256)
            a4[i] = z;
        return;
    }
    if (b < G_MS + G_PK) {
        int c = (b - G_MS) * 256 + threadIdx.x;
        if (c < 65536) {
            int lane = c & 63, mt = (c >> 6) & 3, ks = (c >> 8) & 3, j = c >> 10;
            int i   = mt * 16 + (lane & 15);
            int col = ks * 32 + ((lane >> 4) & 3) * 8;
            const float* src = W2 + (size_t)(i * 64 + j) * HID + col;
            half8 o;
#pragma unroll
            for (int q = 0; q < 8; ++q) o[q] = (_Float16)src[q];
            ((half8*)Wpk)[c] = o;
        } else if (c < 65536 + 512) {
            int c2 = c - 65536;
            int lane = c2 & 63, mt = (c2 >> 6) & 3, ks2 = (c2 >> 8) & 1;
            int i = mt * 16 + (lane & 15);
            int j = ks2 * 32 + ((lane >> 4) & 3) * 8;
            const float* src = b2 + i * 64 + j;
            half8 o;
#pragma unroll
            for (int q = 0; q < 8; ++q) o[q] = (_Float16)src[q];
            ((half8*)b2pk)[c2] = o;
        } else if (c < 65536 + 512 + 2 * 12288) {
            int idx = c - (65536 + 512);
            const float* src = (idx < 12288) ? w_ih : w_hh;
            float*       dst = (idx < 12288) ? wTih : wThh;
            int e2 = (idx < 12288) ? idx : idx - 12288;
            int k = e2 / 192, g = e2 - k * 192;
            dst[k * 192 + g] = src[(size_t)g * 64 + k];
        }
        return;
    }
    // mlp1: 8 edges per block
    int ebase = (b - G_MS - G_PK) * 8;
    int k = threadIdx.x & 127;
    const float* w = W1 + (size_t)k * EDGE_DIM;
#pragma unroll
    for (int p = 0; p < 4; ++p) {
        int e = ebase + p * 2 + (threadIdx.x >> 7);
        if (e >= N_EDGES) break;
        const float* ea = edge_attr + (size_t)e * EDGE_DIM;
        float acc = b1[k];
#pragma unroll
        for (int d = 0; d < EDGE_DIM; ++d) acc += ea[d] * w[d];
        float g = 0.5f * acc * (1.0f + erff(acc * 0.70710678118654752f));
        h[(size_t)e * HID + k] = (_Float16)g;
    }
}

// ---------------------------------------------------------------- phase 2
// 8 waves: wave = (kh, mt). Wave mt owns i-rows [mt*16,mt*16+16); kh owns
// K-half (k in [kh*64, kh*64+64), i.e. ks chunks {kh*2, kh*2+1}).
// Per j: 2 prefetched A-loads, 8 MFMA (chain len 2), f32 gv epilogue on the
// K-partial P. Partial msgs combine in dual msgred at scatter.
__global__ __launch_bounds__(512, 2) void edge_msg_mfma_kernel(
    const _Float16* __restrict__ hbuf,
    const float*    __restrict__ x,
    const int*      __restrict__ edge_index,   // [2][E] int32
    const _Float16* __restrict__ Wpk,
    const _Float16* __restrict__ b2pk,
    float* __restrict__ agg)                   // [N][64], pre-zeroed
{
    __shared__ float xsh[64 * 68];        // gathered x[src], pitch 68
    __shared__ float msgred[2][64 * 67];  // [kh][i][e], pitch 67
    __shared__ int   dsts[64];

    const int e0   = blockIdx.x * 64;
    const int t    = threadIdx.x;
    const int wave = t >> 6;
    const int lane = t & 63;
    const int mt   = wave & 3;          // i-row block
    const int kh   = wave >> 2;         // K half

    // ---- gather x[src[e]] rows into xsh (zero-fill invalid) + dsts
    if (t < 64) dsts[t] = (e0 + t < N_EDGES) ? edge_index[N_EDGES + e0 + t] : -1;
#pragma unroll
    for (int r = 0; r < 2; ++r) {
        int idx = t + r * 512;            // 0..1023 float4 slots
        int le = idx >> 4, q = idx & 15;
        int e = e0 + le;
        float4 v = make_float4(0.f, 0.f, 0.f, 0.f);
        if (e < N_EDGES) {
            int s = edge_index[e];
            if ((unsigned)s < (unsigned)N_NODES)
                v = ((const float4*)x)[(size_t)s * 16 + q];
        }
        *(float4*)&xsh[le * 68 + q * 4] = v;
    }

    // ---- per-wave resident h fragments: this wave's K-half only
    half8 hf[4][2];   // [nt][kk], ks_global = kh*2 + kk
#pragma unroll
    for (int nt = 0; nt < 4; ++nt) {
#pragma unroll
        for (int kk = 0; kk < 2; ++kk) {
            int el = nt * 16 + (lane & 15);
            int ee = e0 + el; if (ee >= N_EDGES) ee = N_EDGES - 1;
            int gk = (kh * 2 + kk) * 32 + ((lane >> 4) & 3) * 8;
            hf[nt][kk] = *(const half8*)(hbuf + (size_t)ee * HID + gk);
        }
    }
    __syncthreads();

    const f32x4 zero4 = {0.f, 0.f, 0.f, 0.f};
    f32x4 msg[4];
#pragma unroll
    for (int nt = 0; nt < 4; ++nt) msg[nt] = zero4;

    const half8* wpk8 = (const half8*)Wpk;
    const size_t kbase = (size_t)mt * 64 + lane + (size_t)(kh * 2) * 256;

    half8 aA[2], aB[2];
#pragma unroll
    for (int kk = 0; kk < 2; ++kk) aA[kk] = wpk8[kbase + kk * 256];   // j=0

#pragma unroll 1
    for (int j = 0; j < 64; j += 2) {
        {   // prefetch j+1
            size_t nb = (size_t)(j + 1) * 1024 + kbase;
#pragma unroll
            for (int kk = 0; kk < 2; ++kk) aB[kk] = wpk8[nb + kk * 256];
        }
        {   // compute j
            float gv[4];
#pragma unroll
            for (int nt = 0; nt < 4; ++nt) gv[nt] = xsh[(nt * 16 + (lane & 15)) * 68 + j];
            f32x4 P[4];
#pragma unroll
            for (int kk = 0; kk < 2; ++kk)
#pragma unroll
                for (int nt = 0; nt < 4; ++nt)
                    P[nt] = __builtin_amdgcn_mfma_f32_16x16x32_f16(
                        aA[kk], hf[nt][kk], kk == 0 ? zero4 : P[nt], 0, 0, 0);
#pragma unroll
            for (int nt = 0; nt < 4; ++nt)
#pragma unroll
                for (int r = 0; r < 4; ++r) msg[nt][r] += gv[nt] * P[nt][r];
        }
        if (j + 2 < 64) {   // prefetch j+2
            size_t nb = (size_t)(j + 2) * 1024 + kbase;
#pragma unroll
            for (int kk = 0; kk < 2; ++kk) aA[kk] = wpk8[nb + kk * 256];
        }
        {   // compute j+1
            float gv[4];
#pragma unroll
            for (int nt = 0; nt < 4; ++nt) gv[nt] = xsh[(nt * 16 + (lane & 15)) * 68 + j + 1];
            f32x4 P[4];
#pragma unroll
            for (int kk = 0; kk < 2; ++kk)
#pragma unroll
                for (int nt = 0; nt < 4; ++nt)
                    P[nt] = __builtin_amdgcn_mfma_f32_16x16x32_f16(
                        aB[kk], hf[nt][kk], kk == 0 ? zero4 : P[nt], 0, 0, 0);
#pragma unroll
            for (int nt = 0; nt < 4; ++nt)
#pragma unroll
                for (int r = 0; r < 4; ++r) msg[nt][r] += gv[nt] * P[nt][r];
        }
    }

    // ---- bias: wave kh handles its 32-j chunk (ks2 = kh)
    {
        const int ks2 = kh;
        half8 gf[4];
#pragma unroll
        for (int nt = 0; nt < 4; ++nt) {
            const float* gp = &xsh[(nt * 16 + (lane & 15)) * 68 + ks2 * 32 + ((lane >> 4) & 3) * 8];
            float4 lo = *(const float4*)gp;
            float4 hi = *(const float4*)(gp + 4);
            half8 g8;
            g8[0] = (_Float16)lo.x; g8[1] = (_Float16)lo.y;
            g8[2] = (_Float16)lo.z; g8[3] = (_Float16)lo.w;
            g8[4] = (_Float16)hi.x; g8[5] = (_Float16)hi.y;
            g8[6] = (_Float16)hi.z; g8[7] = (_Float16)hi.w;
            gf[nt] = g8;
        }
        half8 bf8 = ((const half8*)b2pk)[ks2 * 256 + mt * 64 + lane];
#pragma unroll
        for (int nt = 0; nt < 4; ++nt)
            msg[nt] = __builtin_amdgcn_mfma_f32_16x16x32_f16(bf8, gf[nt], msg[nt], 0, 0, 0);
    }

    // ---- each wave writes its exclusive 16 rows of msgred[kh]
#pragma unroll
    for (int nt = 0; nt < 4; ++nt)
#pragma unroll
        for (int r = 0; r < 4; ++r) {
            int i = mt * 16 + ((lane >> 4) & 3) * 4 + r;
            int e = nt * 16 + (lane & 15);
            msgred[kh][i * 67 + e] = msg[nt][r];
        }
    __syncthreads();

    // ---- scatter: sum the two K-halves, one edge row per atomic instr
#pragma unroll 1
    for (int ee = wave; ee < 64; ee += 8) {
        int d = dsts[ee];
        if (e0 + ee < N_EDGES && (unsigned)d < (unsigned)N_NODES) {
            float v = msgred[0][lane * 67 + ee] + msgred[1][lane * 67 + ee];
            atomicAdd(agg + (size_t)d * NODE_DIM + lane, v);
        }
    }
}

// ---------------------------------------------------------------- phase 3
// GRUCell, transposed-LDS staging (r9, proven).
__global__ __launch_bounds__(256) void gru_kernel(
    const float* __restrict__ agg,
    const float* __restrict__ x,
    const float* __restrict__ wTih,   // [64][192]
    const float* __restrict__ wThh,   // [64][192]
    const float* __restrict__ b_ih,
    const float* __restrict__ b_hh,
    float* __restrict__ out)
{
    __shared__ float asT[4][64][12];  // [wave][k][node]
    __shared__ float xsT[4][64][12];
    const int t    = threadIdx.x;
    const int wave = t >> 6, lane = t & 63;
    const int n0   = blockIdx.x * 32;

    {
        const f32x4* asrc = (const f32x4*)(agg + (size_t)n0 * 64);
        const f32x4* xsrc = (const f32x4*)(x   + (size_t)n0 * 64);
        int nvalid4 = min(N_NODES - n0, 32) * 16;
#pragma unroll
        for (int r = 0; r < 2; ++r) {
            int idx = t + r * 256;
            f32x4 v = {0.f, 0.f, 0.f, 0.f}, u = v;
            if (idx < nvalid4) { v = asrc[idx]; u = xsrc[idx]; }
            int le = idx >> 4, q = idx & 15;
#pragma unroll
            for (int c = 0; c < 4; ++c) {
                asT[le >> 3][q * 4 + c][le & 7] = v[c];
                xsT[le >> 3][q * 4 + c][le & 7] = u[c];
            }
        }
    }
    __syncthreads();

    float accI0[8] = {}, accI1[8] = {}, accI2[8] = {};
    float accH0[8] = {}, accH1[8] = {}, accH2[8] = {};

#pragma unroll 4
    for (int k = 0; k < 64; ++k) {
        f32x4 a03 = *(const f32x4*)&asT[wave][k][0];
        f32x4 a47 = *(const f32x4*)&asT[wave][k][4];
        f32x4 x03 = *(const f32x4*)&xsT[wave][k][0];
        f32x4 x47 = *(const f32x4*)&xsT[wave][k][4];
        float wi0 = wTih[k * 192 + lane];
        float wi1 = wTih[k * 192 + 64 + lane];
        float wi2 = wTih[k * 192 + 128 + lane];
        float wh0 = wThh[k * 192 + lane];
        float wh1 = wThh[k * 192 + 64 + lane];
        float wh2 = wThh[k * 192 + 128 + lane];
#pragma unroll
        for (int n = 0; n < 8; ++n) {
            float a  = (n < 4) ? a03[n] : a47[n - 4];
            float xx = (n < 4) ? x03[n] : x47[n - 4];
            accI0[n] += a * wi0;  accI1[n] += a * wi1;  accI2[n] += a * wi2;
            accH0[n] += xx * wh0; accH1[n] += xx * wh1; accH2[n] += xx * wh2;
        }
    }

    float bi0 = b_ih[lane], bi1 = b_ih[64 + lane], bi2 = b_ih[128 + lane];
    float bh0 = b_hh[lane], bh1 = b_hh[64 + lane], bh2 = b_hh[128 + lane];
#pragma unroll
    for (int n = 0; n < 8; ++n) {
        int node = n0 + wave * 8 + n;
        if (node >= N_NODES) break;
        float r  = 1.f / (1.f + expf(-(accI0[n] + bi0 + accH0[n] + bh0)));
        float z  = 1.f / (1.f + expf(-(accI1[n] + bi1 + accH1[n] + bh1)));
        float nn = tanhf(accI2[n] + bi2 + r * (accH2[n] + bh2));
        float xv = x[(size_t)node * 64 + lane];
        out[(size_t)node * 64 + lane] = (1.f - z) * nn + z * xv;
    }
}

// ---------------------------------------------------------------- launch
extern "C" void kernel_launch(void* const* d_in, const int* in_sizes, int n_in,
                              void* d_out, int out_size, void* d_ws, size_t ws_size,
                              hipStream_t stream)
{
    const float* x          = (const float*)d_in[0];
    const int*   edge_index = (const int*)  d_in[1];
    const float* edge_attr  = (const float*)d_in[2];
    const float* W1         = (const float*)d_in[3];
    const float* b1         = (const float*)d_in[4];
    const float* W2         = (const float*)d_in[5];
    const float* b2         = (const float*)d_in[6];
    const float* w_ih       = (const float*)d_in[7];
    const float* w_hh       = (const float*)d_in[8];
    const float* b_ih       = (const float*)d_in[9];
    const float* b_hh       = (const float*)d_in[10];
    float* out = (float*)d_out;

    // ws layout: byte-identical to round 5/9 (proven; total 20,355,072 B)
    char* ws = (char*)d_ws;
    _Float16* hbuf = (_Float16*)ws;                         // 12.8 MB
    ws += (size_t)N_EDGES * HID * sizeof(_Float16);
    _Float16* Wpk  = (_Float16*)ws;                         // 1 MB
    ws += (size_t)65536 * 8 * sizeof(_Float16);
    _Float16* b2pk = (_Float16*)ws;                         // 8 KB
    ws += (size_t)512 * 8 * sizeof(_Float16);
    float* wTih = (float*)ws;                               // 48 KB
    ws += (size_t)64 * 192 * sizeof(float);
    float* wThh = (float*)ws;                               // 48 KB
    ws += (size_t)64 * 192 * sizeof(float);
    float* agg = (float*)ws;                                // 6.4 MB

    prep_kernel<<<dim3(G_MS + G_PK + G_MLP), dim3(256), 0, stream>>>(
        W2, b2, w_ih, w_hh, edge_attr, W1, b1,
        Wpk, b2pk, wTih, wThh, hbuf, agg);

    edge_msg_mfma_kernel<<<dim3((N_EDGES + 63) / 64), dim3(512), 0, stream>>>(
        hbuf, x, edge_index, Wpk, b2pk, agg);

    gru_kernel<<<dim3((N_NODES + 31) / 32), dim3(256), 0, stream>>>(
        agg, x, wTih, wThh, b_ih, b_hh, out);
}

// Round 13
// 121.177 us; speedup vs baseline: 1.1588x; 1.0473x over previous
//
#include <hip/hip_runtime.h>
#include <math.h>

// EdgeConditionedConv on MI355X — round 12: LDS-staged A (global_load_lds,
// double-buffered, 1 barrier/j) + 128-edge blocks.
// r5-r11 post-mortem: three wave-structures all pinned at MFMA-busy ~22us
// with duty <=31%; occupancy raises didn't help -> limiter is per-wave L2
// latency exposure + full-1MB-Wpk-per-64-edges restreaming. This round:
// A j-slice staged async into LDS shared by all 8 waves; 128 edges/block
// halves L2 A-traffic; prefetch rides across barriers (T3-lite).
// prep/gru = r9 (proven). ws layout = r5/r9 byte-identical.

constexpr int N_NODES  = 25000;
constexpr int N_EDGES  = 50000;
constexpr int NODE_DIM = 64;
constexpr int EDGE_DIM = 16;
constexpr int HID      = 128;
constexpr int BE       = 128;          // edges per edge_msg block

typedef __attribute__((ext_vector_type(8))) _Float16 half8;
typedef __attribute__((ext_vector_type(4))) float    f32x4;

constexpr int G_MS  = 128;             // agg-zero blocks
constexpr int G_PK  = 355;             // prepack blocks
constexpr int G_MLP = N_EDGES / 8;     // mlp1 blocks (8 edges each)

__device__ inline void gload_lds16(const void* g, void* l) {
    __builtin_amdgcn_global_load_lds(
        (const __attribute__((address_space(1))) unsigned int*)g,
        (__attribute__((address_space(3))) unsigned int*)l, 16, 0, 0);
}

// ---------------------------------------------------------------- prep
__global__ __launch_bounds__(256) void prep_kernel(
    const float* __restrict__ W2, const float* __restrict__ b2,
    const float* __restrict__ w_ih, const float* __restrict__ w_hh,
    const float* __restrict__ edge_attr, const float* __restrict__ W1,
    const float* __restrict__ b1,
    _Float16* __restrict__ Wpk, _Float16* __restrict__ b2pk,
    float* __restrict__ wTih, float* __restrict__ wThh,
    _Float16* __restrict__ h, float* __restrict__ agg)
{
    int b = blockIdx.x;
    if (b < G_MS) {
        float4* a4 = (float4*)agg;
        const float4 z = make_float4(0.f, 0.f, 0.f, 0.f);
        for (int i = b * 256 + threadIdx.x; i < N_NODES * NODE_DIM / 4; i += G_MS * 256)
            a4[i] = z;
        return;
    }
    if (b < G_MS + G_PK) {
        int c = (b - G_MS) * 256 + threadIdx.x;
        if (c < 65536) {
            int lane = c & 63, mt = (c >> 6) & 3, ks = (c >> 8) & 3, j = c >> 10;
            int i   = mt * 16 + (lane & 15);
            int col = ks * 32 + ((lane >> 4) & 3) * 8;
            const float* src = W2 + (size_t)(i * 64 + j) * HID + col;
            half8 o;
#pragma unroll
            for (int q = 0; q < 8; ++q) o[q] = (_Float16)src[q];
            ((half8*)Wpk)[c] = o;
        } else if (c < 65536 + 512) {
            int c2 = c - 65536;
            int lane = c2 & 63, mt = (c2 >> 6) & 3, ks2 = (c2 >> 8) & 1;
            int i = mt * 16 + (lane & 15);
            int j = ks2 * 32 + ((lane >> 4) & 3) * 8;
            const float* src = b2 + i * 64 + j;
            half8 o;
#pragma unroll
            for (int q = 0; q < 8; ++q) o[q] = (_Float16)src[q];
            ((half8*)b2pk)[c2] = o;
        } else if (c < 65536 + 512 + 2 * 12288) {
            int idx = c - (65536 + 512);
            const float* src = (idx < 12288) ? w_ih : w_hh;
            float*       dst = (idx < 12288) ? wTih : wThh;
            int e2 = (idx < 12288) ? idx : idx - 12288;
            int k = e2 / 192, g = e2 - k * 192;
            dst[k * 192 + g] = src[(size_t)g * 64 + k];
        }
        return;
    }
    // mlp1: 8 edges per block
    int ebase = (b - G_MS - G_PK) * 8;
    int k = threadIdx.x & 127;
    const float* w = W1 + (size_t)k * EDGE_DIM;
#pragma unroll
    for (int p = 0; p < 4; ++p) {
        int e = ebase + p * 2 + (threadIdx.x >> 7);
        if (e >= N_EDGES) break;
        const float* ea = edge_attr + (size_t)e * EDGE_DIM;
        float acc = b1[k];
#pragma unroll
        for (int d = 0; d < EDGE_DIM; ++d) acc += ea[d] * w[d];
        float g = 0.5f * acc * (1.0f + erff(acc * 0.70710678118654752f));
        h[(size_t)e * HID + k] = (_Float16)g;
    }
}

// ---------------------------------------------------------------- phase 2
// 8 waves: wave = (eh, mt). mt = 16 i-rows, eh = 64-edge half of the 128.
// A j-slice (16 KB) double-buffered in LDS via global_load_lds; all waves
// stage cooperatively (2 x 1KB rows each), consume shared fragments.
__global__ __launch_bounds__(512, 2) void edge_msg_mfma_kernel(
    const _Float16* __restrict__ hbuf,
    const float*    __restrict__ x,
    const int*      __restrict__ edge_index,   // [2][E] int32
    const _Float16* __restrict__ Wpk,
    const _Float16* __restrict__ b2pk,
    float* __restrict__ agg)                   // [N][64], pre-zeroed
{
    __shared__ __align__(16) char Asl[2][16384];   // A j-slice double buffer
    __shared__ float xsh[BE * 68];                 // gathered x[src], pitch 68
    __shared__ int   dsts[BE];
    float* msgred = xsh;                           // alias: [i][e] 64 x 130

    const int e0   = blockIdx.x * BE;
    const int t    = threadIdx.x;
    const int wave = t >> 6;
    const int lane = t & 63;
    const int mt   = wave & 3;          // i-row block
    const int eh   = wave >> 2;         // edge half

    // ---- gather x[src[e]] rows into xsh (zero-fill invalid) + dsts
    if (t < BE) dsts[t] = (e0 + t < N_EDGES) ? edge_index[N_EDGES + e0 + t] : -1;
#pragma unroll
    for (int r = 0; r < 4; ++r) {
        int idx = t + r * 512;            // 0..2047 float4 slots
        int le = idx >> 4, q = idx & 15;
        int e = e0 + le;
        float4 v = make_float4(0.f, 0.f, 0.f, 0.f);
        if (e < N_EDGES) {
            int s = edge_index[e];
            if ((unsigned)s < (unsigned)N_NODES)
                v = ((const float4*)x)[(size_t)s * 16 + q];
        }
        *(float4*)&xsh[le * 68 + q * 4] = v;
    }

    // ---- per-wave resident h fragments for this eh half
    half8 hf[4][4];   // [nt][ks]
#pragma unroll
    for (int nt = 0; nt < 4; ++nt) {
#pragma unroll
        for (int ks = 0; ks < 4; ++ks) {
            int el = eh * 64 + nt * 16 + (lane & 15);
            int ee = e0 + el; if (ee >= N_EDGES) ee = N_EDGES - 1;
            int gk = ks * 32 + ((lane >> 4) & 3) * 8;
            hf[nt][ks] = *(const half8*)(hbuf + (size_t)ee * HID + gk);
        }
    }

    // ---- stage j=0 slice, then sync everything
    {
        const _Float16* gsrc = Wpk + ((size_t)0 * 1024 + wave * 128) * 8;
        char* lb = &Asl[0][wave * 2048];
        gload_lds16(gsrc + (size_t)lane * 8, lb);
        gload_lds16(gsrc + (size_t)(64 + lane) * 8, lb + 1024);
    }
    asm volatile("s_waitcnt vmcnt(0)" ::: "memory");
    __syncthreads();

    const f32x4 zero4 = {0.f, 0.f, 0.f, 0.f};
    f32x4 msg[4];
#pragma unroll
    for (int nt = 0; nt < 4; ++nt) msg[nt] = zero4;

    int cur = 0;
#pragma unroll 1
    for (int j = 0; j < 64; ++j) {
        if (j + 1 < 64) {   // stage next slice into other buffer (async)
            const _Float16* gsrc = Wpk + ((size_t)(j + 1) * 1024 + wave * 128) * 8;
            char* lb = &Asl[cur ^ 1][wave * 2048];
            gload_lds16(gsrc + (size_t)lane * 8, lb);
            gload_lds16(gsrc + (size_t)(64 + lane) * 8, lb + 1024);
        }
        // compute j from Asl[cur]
        float gv[4];
#pragma unroll
        for (int nt = 0; nt < 4; ++nt)
            gv[nt] = xsh[(eh * 64 + nt * 16 + (lane & 15)) * 68 + j];
        const half8* As = (const half8*)&Asl[cur][0];
        f32x4 P[4];
#pragma unroll
        for (int ks = 0; ks < 4; ++ks) {
            half8 av = As[ks * 256 + mt * 64 + lane];
#pragma unroll
            for (int nt = 0; nt < 4; ++nt)
                P[nt] = __builtin_amdgcn_mfma_f32_16x16x32_f16(
                    av, hf[nt][ks], ks == 0 ? zero4 : P[nt], 0, 0, 0);
        }
#pragma unroll
        for (int nt = 0; nt < 4; ++nt)
#pragma unroll
            for (int r = 0; r < 4; ++r) msg[nt][r] += gv[nt] * P[nt][r];

        asm volatile("s_waitcnt vmcnt(0)" ::: "memory");
        __syncthreads();
        cur ^= 1;
    }

    // ---- bias: msg[i,e] += sum_j b2[i*64+j]*g[e,j]  (this wave's tile)
#pragma unroll
    for (int ks2 = 0; ks2 < 2; ++ks2) {
        half8 gf[4];
#pragma unroll
        for (int nt = 0; nt < 4; ++nt) {
            const float* gp = &xsh[(eh * 64 + nt * 16 + (lane & 15)) * 68 + ks2 * 32 + ((lane >> 4) & 3) * 8];
            float4 lo = *(const float4*)gp;
            float4 hi = *(const float4*)(gp + 4);
            half8 g8;
            g8[0] = (_Float16)lo.x; g8[1] = (_Float16)lo.y;
            g8[2] = (_Float16)lo.z; g8[3] = (_Float16)lo.w;
            g8[4] = (_Float16)hi.x; g8[5] = (_Float16)hi.y;
            g8[6] = (_Float16)hi.z; g8[7] = (_Float16)hi.w;
            gf[nt] = g8;
        }
        half8 bf8 = ((const half8*)b2pk)[ks2 * 256 + mt * 64 + lane];
#pragma unroll
        for (int nt = 0; nt < 4; ++nt)
            msg[nt] = __builtin_amdgcn_mfma_f32_16x16x32_f16(bf8, gf[nt], msg[nt], 0, 0, 0);
    }
    __syncthreads();   // all xsh reads done before msgred (alias) writes

    // ---- each wave writes its exclusive 16x64 tile of msgred [64][130]
#pragma unroll
    for (int nt = 0; nt < 4; ++nt)
#pragma unroll
        for (int r = 0; r < 4; ++r) {
            int i = mt * 16 + ((lane >> 4) & 3) * 4 + r;
            int e = eh * 64 + nt * 16 + (lane & 15);
            msgred[i * 130 + e] = msg[nt][r];
        }
    __syncthreads();

    // ---- scatter, coalesced: one edge row per atomic instr (lane = dim i)
#pragma unroll 1
    for (int ee = wave; ee < BE; ee += 8) {
        int d = dsts[ee];
        if (e0 + ee < N_EDGES && (unsigned)d < (unsigned)N_NODES)
            atomicAdd(agg + (size_t)d * NODE_DIM + lane, msgred[lane * 130 + ee]);
    }
}

// ---------------------------------------------------------------- phase 3
// GRUCell, transposed-LDS staging (r9, proven).
__global__ __launch_bounds__(256) void gru_kernel(
    const float* __restrict__ agg,
    const float* __restrict__ x,
    const float* __restrict__ wTih,   // [64][192]
    const float* __restrict__ wThh,   // [64][192]
    const float* __restrict__ b_ih,
    const float* __restrict__ b_hh,
    float* __restrict__ out)
{
    __shared__ float asT[4][64][12];  // [wave][k][node]
    __shared__ float xsT[4][64][12];
    const int t    = threadIdx.x;
    const int wave = t >> 6, lane = t & 63;
    const int n0   = blockIdx.x * 32;

    {
        const f32x4* asrc = (const f32x4*)(agg + (size_t)n0 * 64);
        const f32x4* xsrc = (const f32x4*)(x   + (size_t)n0 * 64);
        int nvalid4 = min(N_NODES - n0, 32) * 16;
#pragma unroll
        for (int r = 0; r < 2; ++r) {
            int idx = t + r * 256;
            f32x4 v = {0.f, 0.f, 0.f, 0.f}, u = v;
            if (idx < nvalid4) { v = asrc[idx]; u = xsrc[idx]; }
            int le = idx >> 4, q = idx & 15;
#pragma unroll
            for (int c = 0; c < 4; ++c) {
                asT[le >> 3][q * 4 + c][le & 7] = v[c];
                xsT[le >> 3][q * 4 + c][le & 7] = u[c];
            }
        }
    }
    __syncthreads();

    float accI0[8] = {}, accI1[8] = {}, accI2[8] = {};
    float accH0[8] = {}, accH1[8] = {}, accH2[8] = {};

#pragma unroll 4
    for (int k = 0; k < 64; ++k) {
        f32x4 a03 = *(const f32x4*)&asT[wave][k][0];
        f32x4 a47 = *(const f32x4*)&asT[wave][k][4];
        f32x4 x03 = *(const f32x4*)&xsT[wave][k][0];
        f32x4 x47 = *(const f32x4*)&xsT[wave][k][4];
        float wi0 = wTih[k * 192 + lane];
        float wi1 = wTih[k * 192 + 64 + lane];
        float wi2 = wTih[k * 192 + 128 + lane];
        float wh0 = wThh[k * 192 + lane];
        float wh1 = wThh[k * 192 + 64 + lane];
        float wh2 = wThh[k * 192 + 128 + lane];
#pragma unroll
        for (int n = 0; n < 8; ++n) {
            float a  = (n < 4) ? a03[n] : a47[n - 4];
            float xx = (n < 4) ? x03[n] : x47[n - 4];
            accI0[n] += a * wi0;  accI1[n] += a * wi1;  accI2[n] += a * wi2;
            accH0[n] += xx * wh0; accH1[n] += xx * wh1; accH2[n] += xx * wh2;
        }
    }

    float bi0 = b_ih[lane], bi1 = b_ih[64 + lane], bi2 = b_ih[128 + lane];
    float bh0 = b_hh[lane], bh1 = b_hh[64 + lane], bh2 = b_hh[128 + lane];
#pragma unroll
    for (int n = 0; n < 8; ++n) {
        int node = n0 + wave * 8 + n;
        if (node >= N_NODES) break;
        float r  = 1.f / (1.f + expf(-(accI0[n] + bi0 + accH0[n] + bh0)));
        float z  = 1.f / (1.f + expf(-(accI1[n] + bi1 + accH1[n] + bh1)));
        float nn = tanhf(accI2[n] + bi2 + r * (accH2[n] + bh2));
        float xv = x[(size_t)node * 64 + lane];
        out[(size_t)node * 64 + lane] = (1.f - z) * nn + z * xv;
    }
}

// ---------------------------------------------------------------- launch
extern "C" void kernel_launch(void* const* d_in, const int* in_sizes, int n_in,
                              void* d_out, int out_size, void* d_ws, size_t ws_size,
                              hipStream_t stream)
{
    const float* x          = (const float*)d_in[0];
    const int*   edge_index = (const int*)  d_in[1];
    const float* edge_attr  = (const float*)d_in[2];
    const float* W1         = (const float*)d_in[3];
    const float* b1         = (const float*)d_in[4];
    const float* W2         = (const float*)d_in[5];
    const float* b2         = (const float*)d_in[6];
    const float* w_ih       = (const float*)d_in[7];
    const float* w_hh       = (const float*)d_in[8];
    const float* b_ih       = (const float*)d_in[9];
    const float* b_hh       = (const float*)d_in[10];
    float* out = (float*)d_out;

    // ws layout: byte-identical to round 5/9 (proven; total 20,355,072 B)
    char* ws = (char*)d_ws;
    _Float16* hbuf = (_Float16*)ws;                         // 12.8 MB
    ws += (size_t)N_EDGES * HID * sizeof(_Float16);
    _Float16* Wpk  = (_Float16*)ws;                         // 1 MB
    ws += (size_t)65536 * 8 * sizeof(_Float16);
    _Float16* b2pk = (_Float16*)ws;                         // 8 KB
    ws += (size_t)512 * 8 * sizeof(_Float16);
    float* wTih = (float*)ws;                               // 48 KB
    ws += (size_t)64 * 192 * sizeof(float);
    float* wThh = (float*)ws;                               // 48 KB
    ws += (size_t)64 * 192 * sizeof(float);
    float* agg = (float*)ws;                                // 6.4 MB

    prep_kernel<<<dim3(G_MS + G_PK + G_MLP), dim3(256), 0, stream>>>(
        W2, b2, w_ih, w_hh, edge_attr, W1, b1,
        Wpk, b2pk, wTih, wThh, hbuf, agg);

    edge_msg_mfma_kernel<<<dim3((N_EDGES + BE - 1) / BE), dim3(512), 0, stream>>>(
        hbuf, x, edge_index, Wpk, b2pk, agg);

    gru_kernel<<<dim3((N_NODES + 31) / 32), dim3(256), 0, stream>>>(
        agg, x, wTih, wThh, b_ih, b_hh, out);
}